// Round 5
// baseline (1513.655 us; speedup 1.0000x reference)
//
#include <hip/hip_runtime.h>
#include <math.h>

typedef _Float16 f16;
typedef __attribute__((ext_vector_type(8))) _Float16 half8;
typedef __attribute__((ext_vector_type(4))) float float4v;

// ---------------- helpers ----------------
__device__ __forceinline__ float fast_sigmoid(float x) { return 1.0f / (1.0f + __expf(-x)); }
__device__ __forceinline__ float fast_tanh(float x) {
    float a = fabsf(x);
    float e = __expf(-2.0f * a);
    float t = (1.0f - e) / (1.0f + e);
    return copysignf(t, x);
}

// async global->LDS, 16B per lane. LDS dest = wave-uniform base + lane*16.
__device__ __forceinline__ void async_copy16(const void* gsrc, void* ldst) {
    __builtin_amdgcn_global_load_lds(
        (const __attribute__((address_space(1))) void*)gsrc,
        (__attribute__((address_space(3))) void*)ldst,
        16, 0, 0);
}

// ---------------- prep kernels ----------------
// Gate-permuted fp16 weights: Bp[col'][k], col' = dg*64 + q*16 + dl
// original gate-row j = q*128 + dg*16 + dl. k<Kih -> Wih[j][k], else Whh[j][k-Kih].
__global__ void packb_kernel(const float* __restrict__ Wih, int Kih,
                             const float* __restrict__ Whh, int K,
                             const float* __restrict__ bih, const float* __restrict__ bhh,
                             f16* __restrict__ Bp, float* __restrict__ bp) {
    int t = blockIdx.x * blockDim.x + threadIdx.x;
    if (t >= (K << 9)) return;
    int colp = t / K;
    int k = t - colp * K;
    int dg = colp >> 6, q = (colp >> 4) & 3, dl = colp & 15;
    int j = q * 128 + dg * 16 + dl;
    float v = (k < Kih) ? Wih[j * Kih + k] : Whh[j * (K - Kih) + (k - Kih)];
    Bp[t] = (f16)v;
    if (k == 0) bp[colp] = bih[j] + bhh[j];
}

__global__ void feat0_kernel(const float* __restrict__ features, const float* __restrict__ W_in,
                             const float* __restrict__ b_in, f16* __restrict__ feat, int n) {
    int t = blockIdx.x * blockDim.x + threadIdx.x;
    if (t >= n * 128) return;
    int node = t >> 7;
    int d = t & 127;
    float s = b_in[d];
#pragma unroll
    for (int k = 0; k < 6; ++k) s += features[node * 6 + k] * W_in[k * 128 + d];
    feat[t] = (f16)fmaxf(s, 0.0f);
}

__global__ void hist_kernel(const int* __restrict__ dst, int* __restrict__ cnt, int e) {
    int t = blockIdx.x * blockDim.x + threadIdx.x;
    if (t < e) atomicAdd(&cnt[dst[t]], 1);
}

// parallel block-wide scan: wave shuffle scan + wave partials
__global__ void scan_kernel(const int* __restrict__ cnt, int* __restrict__ off,
                            int* __restrict__ cur, float* __restrict__ recip, int n) {
    __shared__ int wsum[16];
    int t = threadIdx.x;  // 1024
    int chunk = (n + 1023) >> 10;
    int s0 = t * chunk;
    int s1 = s0 + chunk; if (s1 > n) s1 = n;
    if (s0 > n) s0 = n;
    int s = 0;
    for (int i = s0; i < s1; ++i) s += cnt[i];
    int lane = t & 63, wv = t >> 6;
    int v = s;
#pragma unroll
    for (int o = 1; o < 64; o <<= 1) {
        int u = __shfl_up(v, o, 64);
        if (lane >= o) v += u;
    }
    if (lane == 63) wsum[wv] = v;
    __syncthreads();
    if (t == 0) {
        int a = 0;
#pragma unroll
        for (int i = 0; i < 16; ++i) { int x = wsum[i]; wsum[i] = a; a += x; }
    }
    __syncthreads();
    int acc = wsum[wv] + v - s;   // exclusive prefix of this thread's chunk
    for (int i = s0; i < s1; ++i) {
        off[i] = acc; cur[i] = acc;
        int cc = cnt[i];
        recip[i] = cc > 0 ? 1.0f / (float)cc : 0.0f;
        acc += cc;
    }
    if (t == 1023) off[n] = acc;
}

__global__ void scatter_kernel(const int* __restrict__ src, const int* __restrict__ dst,
                               int* __restrict__ cur, int* __restrict__ esrc, int e) {
    int t = blockIdx.x * blockDim.x + threadIdx.x;
    if (t >= e) return;
    int d = dst[t];
    int p = atomicAdd(&cur[d], 1);
    esrc[p] = src[t];
}

// mean aggregation: 16 lanes (8 halves each) per node, 16 nodes/block, fp32 accum.
__global__ void agg_kernel(const f16* __restrict__ feat, const int* __restrict__ off,
                           const int* __restrict__ esrc, const float* __restrict__ recip,
                           f16* __restrict__ agg, int n) {
    int slot = threadIdx.x >> 4;
    int lane = threadIdx.x & 15;
    int v = blockIdx.x * 16 + slot;
    if (v >= n) return;
    int e0 = off[v], e1 = off[v + 1];
    float a[8];
#pragma unroll
    for (int j = 0; j < 8; ++j) a[j] = 0.0f;
    int e = e0;
    for (; e + 4 <= e1; e += 4) {
        int s0 = esrc[e], s1 = esrc[e + 1], s2 = esrc[e + 2], s3 = esrc[e + 3];
        half8 v0 = *(const half8*)&feat[(size_t)s0 * 128 + lane * 8];
        half8 v1 = *(const half8*)&feat[(size_t)s1 * 128 + lane * 8];
        half8 v2 = *(const half8*)&feat[(size_t)s2 * 128 + lane * 8];
        half8 v3 = *(const half8*)&feat[(size_t)s3 * 128 + lane * 8];
#pragma unroll
        for (int j = 0; j < 8; ++j)
            a[j] += (float)v0[j] + (float)v1[j] + (float)v2[j] + (float)v3[j];
    }
    for (; e < e1; ++e) {
        int s = esrc[e];
        half8 v0 = *(const half8*)&feat[(size_t)s * 128 + lane * 8];
#pragma unroll
        for (int j = 0; j < 8; ++j) a[j] += (float)v0[j];
    }
    float r = recip[v];
    half8 o;
#pragma unroll
    for (int j = 0; j < 8; ++j) o[j] = (f16)(a[j] * r);
    *(half8*)&agg[(size_t)v * 128 + lane * 8] = o;
}

// ---------------- fused 3-layer LSTM step ----------------
// Block: 256 threads (4 waves), 64 rows, all 512 permuted gate-cols.
// Wave w: col-tiles m = 8w..8w+7 (dims [32w,32w+32), all 4 gates), R=4 row-tiles.
// A-frags: direct global->register (16B/lane). B: LDS-staged, XOR-swizzled.
// NOTE: A0/A1/A2/h/c deliberately NOT __restrict__ — h aliases A2 in layer 0.
#define BM 64

template <int KT>
__device__ __forceinline__ void layer_run(
    const f16* A0, const f16* A1, const f16* A2,
    const f16* __restrict__ Bp, const float* __restrict__ bp,
    float* c, f16* h,
    f16* Bs, int row0, int nrows) {
    constexpr int K = KT * 32;
    const int tid = threadIdx.x;
    const int w = tid >> 6;
    const int lane = tid & 63;
    const int dl = lane & 15;
    const int quad = lane >> 4;

    float4v acc[4][8];  // [row-tile][col-tile j]; j = hh*4 + gate q
#pragma unroll
    for (int j = 0; j < 8; ++j) {
        float b = bp[w * 128 + j * 16 + dl];
#pragma unroll
        for (int rt = 0; rt < 4; ++rt) {
            acc[rt][j][0] = b; acc[rt][j][1] = b; acc[rt][j][2] = b; acc[rt][j][3] = b;
        }
    }

    // staging decomposition: lane -> (col-within-tile sdl, k-slot sj); fetch k-group sg
    const int sdl = lane >> 2;
    const int sj = lane & 3;
    const int sg = sj ^ (sdl & 3);
    // frag-read swizzled k-group offset (halves)
    const int rdoff = (dl << 5) + ((quad ^ (dl & 3)) << 3);

    for (int kt = 0; kt < KT; ++kt) {
        const f16* Ap = A0;
        const int pi = kt >> 2;
        if (pi == 1) Ap = A1;
        if (pi == 2) Ap = A2;
        const int kk = (kt & 3) * 32;   // A-part-local k offset (each part has 128 cols)

        __syncthreads();  // all waves done reading previous Bs tile
        // stage B: 8 col-tiles per wave (its own tiles). B k-offset is GLOBAL: kt*32.
#pragma unroll
        for (int i = 0; i < 8; ++i) {
            int m = (w << 3) + i;
            async_copy16(Bp + (size_t)(m * 16 + sdl) * K + kt * 32 + (sg << 3),
                         Bs + (m << 9));
        }
        // A-frags direct from global (L1-hot 4KB slice)
        half8 a[4];
#pragma unroll
        for (int rt = 0; rt < 4; ++rt)
            a[rt] = *(const half8*)&Ap[(size_t)(row0 + rt * 16 + dl) * 128 + kk + (quad << 3)];
        __syncthreads();  // staging drained (vmcnt 0)

#pragma unroll
        for (int hh = 0; hh < 2; ++hh) {
            half8 b[4];
#pragma unroll
            for (int q = 0; q < 4; ++q) {
                int m = (w << 3) + (hh << 2) + q;
                b[q] = *(const half8*)&Bs[(m << 9) + rdoff];
            }
#pragma unroll
            for (int rt = 0; rt < 4; ++rt)
#pragma unroll
                for (int q = 0; q < 4; ++q)
                    acc[rt][(hh << 2) + q] =
                        __builtin_amdgcn_mfma_f32_16x16x32_f16(a[rt], b[q], acc[rt][(hh << 2) + q], 0, 0, 0);
        }
    }

    // epilogue: wave w owns dims [32w, 32w+32); lane-local i,f,g,o
#pragma unroll
    for (int hh = 0; hh < 2; ++hh) {
        const int d = ((w << 1) + hh) * 16 + dl;
#pragma unroll
        for (int rt = 0; rt < 4; ++rt) {
#pragma unroll
            for (int r = 0; r < 4; ++r) {
                int n = row0 + rt * 16 + (quad << 2) + r;
                if (n < nrows) {
                    float ig = fast_sigmoid(acc[rt][(hh << 2) + 0][r]);
                    float fg = fast_sigmoid(acc[rt][(hh << 2) + 1][r]);
                    float gg = fast_tanh(acc[rt][(hh << 2) + 2][r]);
                    float og = fast_sigmoid(acc[rt][(hh << 2) + 3][r]);
                    float cold = c[(size_t)n * 128 + d];
                    float cn = fg * cold + ig * gg;
                    c[(size_t)n * 128 + d] = cn;
                    h[(size_t)n * 128 + d] = (f16)(og * fast_tanh(cn));
                }
            }
        }
    }
    // next layer's leading __syncthreads orders these stores before its A-loads
}

__global__ __launch_bounds__(256, 2) void fused_lstm_step(
    const f16* __restrict__ aggb, const f16* __restrict__ feat,
    f16* h0, f16* h1, f16* h2,
    float* c0, float* c1, float* c2,
    const f16* __restrict__ B0, const f16* __restrict__ B1, const f16* __restrict__ B2,
    const float* __restrict__ bp0, const float* __restrict__ bp1, const float* __restrict__ bp2,
    int nrows) {
    __shared__ f16 Bs[512 * 32];  // 32 KB, single-buffered per k-iter
    const int row0 = blockIdx.x * BM;
    layer_run<12>(aggb, feat, h0, B0, bp0, c0, h0, Bs, row0, nrows);
    layer_run<8>(h0, h1, nullptr, B1, bp1, c1, h1, Bs, row0, nrows);
    layer_run<8>(h1, h2, nullptr, B2, bp2, c2, h2, Bs, row0, nrows);
}

// ---------------- output projection ----------------
__global__ void out_kernel(const f16* __restrict__ h2, const float* __restrict__ Wout,
                           const float* __restrict__ bout, float* __restrict__ out) {
    int n = blockIdx.x;
    int l = threadIdx.x;  // 0..63
    float v = (float)h2[(size_t)n * 128 + l] * Wout[l] +
              (float)h2[(size_t)n * 128 + 64 + l] * Wout[64 + l];
#pragma unroll
    for (int o = 32; o > 0; o >>= 1) v += __shfl_down(v, o, 64);
    if (l == 0) out[n] = v + bout[0];
}

// ---------------- launch ----------------
extern "C" void kernel_launch(void* const* d_in, const int* in_sizes, int n_in,
                              void* d_out, int out_size, void* d_ws, size_t ws_size,
                              hipStream_t stream) {
    const float* features = (const float*)d_in[0];
    const int*   src      = (const int*)d_in[1];
    const int*   dst      = (const int*)d_in[2];
    const float* W_in     = (const float*)d_in[3];
    const float* b_in     = (const float*)d_in[4];
    const float* Wih0     = (const float*)d_in[5];
    const float* Wih_rest = (const float*)d_in[6];
    const float* Whh      = (const float*)d_in[7];
    const float* bih      = (const float*)d_in[8];
    const float* bhh      = (const float*)d_in[9];
    const float* W_out    = (const float*)d_in[10];
    const float* b_out    = (const float*)d_in[11];
    float* out = (float*)d_out;

    const int N = in_sizes[0] / 6;  // 20000
    const int E = in_sizes[1];      // 640000
    const int NP = N + BM;          // padded rows: staging/A-loads never OOB

    char* ws = (char*)d_ws;
    size_t pos = 0;
    auto alloc = [&](size_t bytes) -> void* {
        void* p = ws + pos;
        pos = (pos + bytes + 255) & ~(size_t)255;
        return p;
    };
    const size_t hrow = 128;
    const size_t hbytes = (size_t)NP * hrow * sizeof(f16);
    const size_t cbytes = (size_t)NP * hrow * sizeof(float);
    f16* feath = (f16*)alloc(hbytes);
    f16* aggh  = (f16*)alloc(hbytes);
    f16* hblk  = (f16*)alloc(3 * hbytes);
    f16* h0 = hblk + 0 * (size_t)NP * hrow;
    f16* h1 = hblk + 1 * (size_t)NP * hrow;
    f16* h2 = hblk + 2 * (size_t)NP * hrow;
    float* cblk = (float*)alloc(3 * cbytes);
    float* c0 = cblk + 0 * (size_t)NP * hrow;
    float* c1 = cblk + 1 * (size_t)NP * hrow;
    float* c2 = cblk + 2 * (size_t)NP * hrow;
    f16* Bp0 = (f16*)alloc((size_t)512 * 384 * sizeof(f16));
    f16* Bp1 = (f16*)alloc((size_t)512 * 256 * sizeof(f16));
    f16* Bp2 = (f16*)alloc((size_t)512 * 256 * sizeof(f16));
    float* bp0 = (float*)alloc(512 * sizeof(float));
    float* bp1 = (float*)alloc(512 * sizeof(float));
    float* bp2 = (float*)alloc(512 * sizeof(float));
    int*   cnt   = (int*)alloc((size_t)N * 4);
    int*   offs  = (int*)alloc((size_t)(N + 1) * 4);
    int*   cur   = (int*)alloc((size_t)N * 4);
    int*   esrc  = (int*)alloc((size_t)E * 4);
    float* recip = (float*)alloc((size_t)N * 4);

    hipMemsetAsync(hblk, 0, 3 * hbytes, stream);
    hipMemsetAsync(cblk, 0, 3 * cbytes, stream);
    hipMemsetAsync(cnt, 0, (size_t)N * 4, stream);

    packb_kernel<<<(512 * 384 + 255) / 256, 256, 0, stream>>>(
        Wih0, 256, Whh, 384, bih, bhh, Bp0, bp0);
    packb_kernel<<<(512 * 256 + 255) / 256, 256, 0, stream>>>(
        Wih_rest, 128, Whh + 512 * 128, 256, bih + 512, bhh + 512, Bp1, bp1);
    packb_kernel<<<(512 * 256 + 255) / 256, 256, 0, stream>>>(
        Wih_rest + 512 * 128, 128, Whh + 2 * 512 * 128, 256, bih + 1024, bhh + 1024, Bp2, bp2);

    feat0_kernel<<<(N * 128 + 255) / 256, 256, 0, stream>>>(features, W_in, b_in, feath, N);
    hist_kernel<<<(E + 255) / 256, 256, 0, stream>>>(dst, cnt, E);
    scan_kernel<<<1, 1024, 0, stream>>>(cnt, offs, cur, recip, N);
    scatter_kernel<<<(E + 255) / 256, 256, 0, stream>>>(src, dst, cur, esrc, E);

    const int gx = (N + BM - 1) / BM;
    const int gagg = (N + 15) / 16;
    const f16* featcur = feath;
    for (int step = 0; step < 11; ++step) {
        agg_kernel<<<gagg, 256, 0, stream>>>(featcur, offs, esrc, recip, aggh, N);
        fused_lstm_step<<<gx, 256, 0, stream>>>(aggh, featcur, h0, h1, h2, c0, c1, c2,
                                                Bp0, Bp1, Bp2, bp0, bp1, bp2, N);
        featcur = h2;
    }
    out_kernel<<<N, 64, 0, stream>>>(h2, W_out, b_out, out);
}

// Round 6
// 1271.806 us; speedup vs baseline: 1.1902x; 1.1902x over previous
//
#include <hip/hip_runtime.h>
#include <math.h>

typedef _Float16 f16;
typedef __attribute__((ext_vector_type(8))) _Float16 half8;
typedef __attribute__((ext_vector_type(4))) float float4v;

// ---------------- helpers ----------------
__device__ __forceinline__ float fast_sigmoid(float x) { return 1.0f / (1.0f + __expf(-x)); }
__device__ __forceinline__ float fast_tanh(float x) {
    float a = fabsf(x);
    float e = __expf(-2.0f * a);
    float t = (1.0f - e) / (1.0f + e);
    return copysignf(t, x);
}

// async global->LDS, 16B per lane. LDS dest = wave-uniform base + lane*16.
__device__ __forceinline__ void async_copy16(const void* gsrc, void* ldst) {
    __builtin_amdgcn_global_load_lds(
        (const __attribute__((address_space(1))) void*)gsrc,
        (__attribute__((address_space(3))) void*)ldst,
        16, 0, 0);
}

// ---------------- prep kernels ----------------
// Gate-permuted fp16 weights: Bp[col'][k], col' = dg*64 + q*16 + dl
// original gate-row j = q*128 + dg*16 + dl. k<Kih -> Wih[j][k], else Whh[j][k-Kih].
__global__ void packb_kernel(const float* __restrict__ Wih, int Kih,
                             const float* __restrict__ Whh, int K,
                             const float* __restrict__ bih, const float* __restrict__ bhh,
                             f16* __restrict__ Bp, float* __restrict__ bp) {
    int t = blockIdx.x * blockDim.x + threadIdx.x;
    if (t >= (K << 9)) return;
    int colp = t / K;
    int k = t - colp * K;
    int dg = colp >> 6, q = (colp >> 4) & 3, dl = colp & 15;
    int j = q * 128 + dg * 16 + dl;
    float v = (k < Kih) ? Wih[j * Kih + k] : Whh[j * (K - Kih) + (k - Kih)];
    Bp[t] = (f16)v;
    if (k == 0) bp[colp] = bih[j] + bhh[j];
}

__global__ void feat0_kernel(const float* __restrict__ features, const float* __restrict__ W_in,
                             const float* __restrict__ b_in, f16* __restrict__ feat, int n) {
    int t = blockIdx.x * blockDim.x + threadIdx.x;
    if (t >= n * 128) return;
    int node = t >> 7;
    int d = t & 127;
    float s = b_in[d];
#pragma unroll
    for (int k = 0; k < 6; ++k) s += features[node * 6 + k] * W_in[k * 128 + d];
    feat[t] = (f16)fmaxf(s, 0.0f);
}

__global__ void hist_kernel(const int* __restrict__ dst, int* __restrict__ cnt, int e) {
    int t = blockIdx.x * blockDim.x + threadIdx.x;
    if (t < e) atomicAdd(&cnt[dst[t]], 1);
}

// parallel block-wide scan: wave shuffle scan + wave partials
__global__ void scan_kernel(const int* __restrict__ cnt, int* __restrict__ off,
                            int* __restrict__ cur, float* __restrict__ recip, int n) {
    __shared__ int wsum[16];
    int t = threadIdx.x;  // 1024
    int chunk = (n + 1023) >> 10;
    int s0 = t * chunk;
    int s1 = s0 + chunk; if (s1 > n) s1 = n;
    if (s0 > n) s0 = n;
    int s = 0;
    for (int i = s0; i < s1; ++i) s += cnt[i];
    int lane = t & 63, wv = t >> 6;
    int v = s;
#pragma unroll
    for (int o = 1; o < 64; o <<= 1) {
        int u = __shfl_up(v, o, 64);
        if (lane >= o) v += u;
    }
    if (lane == 63) wsum[wv] = v;
    __syncthreads();
    if (t == 0) {
        int a = 0;
#pragma unroll
        for (int i = 0; i < 16; ++i) { int x = wsum[i]; wsum[i] = a; a += x; }
    }
    __syncthreads();
    int acc = wsum[wv] + v - s;   // exclusive prefix of this thread's chunk
    for (int i = s0; i < s1; ++i) {
        off[i] = acc; cur[i] = acc;
        int cc = cnt[i];
        recip[i] = cc > 0 ? 1.0f / (float)cc : 0.0f;
        acc += cc;
    }
    if (t == 1023) off[n] = acc;
}

__global__ void scatter_kernel(const int* __restrict__ src, const int* __restrict__ dst,
                               int* __restrict__ cur, int* __restrict__ esrc, int e) {
    int t = blockIdx.x * blockDim.x + threadIdx.x;
    if (t >= e) return;
    int d = dst[t];
    int p = atomicAdd(&cur[d], 1);
    esrc[p] = src[t];
}

// mean aggregation: 16 lanes (8 halves each) per node, 16 nodes/block, fp32 accum.
__global__ void agg_kernel(const f16* __restrict__ feat, const int* __restrict__ off,
                           const int* __restrict__ esrc, const float* __restrict__ recip,
                           f16* __restrict__ agg, int n) {
    int slot = threadIdx.x >> 4;
    int lane = threadIdx.x & 15;
    int v = blockIdx.x * 16 + slot;
    if (v >= n) return;
    int e0 = off[v], e1 = off[v + 1];
    float a[8];
#pragma unroll
    for (int j = 0; j < 8; ++j) a[j] = 0.0f;
    int e = e0;
    for (; e + 4 <= e1; e += 4) {
        int s0 = esrc[e], s1 = esrc[e + 1], s2 = esrc[e + 2], s3 = esrc[e + 3];
        half8 v0 = *(const half8*)&feat[(size_t)s0 * 128 + lane * 8];
        half8 v1 = *(const half8*)&feat[(size_t)s1 * 128 + lane * 8];
        half8 v2 = *(const half8*)&feat[(size_t)s2 * 128 + lane * 8];
        half8 v3 = *(const half8*)&feat[(size_t)s3 * 128 + lane * 8];
#pragma unroll
        for (int j = 0; j < 8; ++j)
            a[j] += (float)v0[j] + (float)v1[j] + (float)v2[j] + (float)v3[j];
    }
    for (; e < e1; ++e) {
        int s = esrc[e];
        half8 v0 = *(const half8*)&feat[(size_t)s * 128 + lane * 8];
#pragma unroll
        for (int j = 0; j < 8; ++j) a[j] += (float)v0[j];
    }
    float r = recip[v];
    half8 o;
#pragma unroll
    for (int j = 0; j < 8; ++j) o[j] = (f16)(a[j] * r);
    *(half8*)&agg[(size_t)v * 128 + lane * 8] = o;
}

// ---------------- MFMA GEMM + LSTM cell (one layer per launch) ----------------
// Block: 128 threads = 2 waves, 64 rows x 256 gate-cols; grid (313, 2).
// Wave w owns 8 col-tiles m = 16*cb + 8*w + j (j = hh*4 + q): dims dg = 4cb+2w+hh,
// all 4 gates -> lane-local epilogue. 32 MFMA per kt per wave.
// B: LDS-staged (wave-private tiles, one barrier/kt, R3's zero-conflict layout).
// A-frags: direct global->register. h ping-pong (h_out never aliases any input).
#define BM 64

template <int KT>
__global__ __launch_bounds__(128, 2) void gemm_lstm(
    const f16* __restrict__ A0, const f16* __restrict__ A1, const f16* __restrict__ A2,
    const f16* __restrict__ Bp, const float* __restrict__ bp,
    float* __restrict__ c, f16* __restrict__ h_out, int nrows) {
    constexpr int K = KT * 32;
    __shared__ f16 Bs[16 * 512];  // 16 KB: 16 col-tiles x (16 dl x 32 k)

    const int tid = threadIdx.x;
    const int w = tid >> 6;       // wave 0..1
    const int lane = tid & 63;
    const int dl = lane & 15;
    const int quad = lane >> 4;
    const int row0 = blockIdx.x * BM;
    const int cb = blockIdx.y;    // 0..1
    const int mb = cb * 16 + w * 8;   // wave's first global col-tile

    float4v acc[4][8];  // [row-tile rt][j = hh*4 + q]
#pragma unroll
    for (int j = 0; j < 8; ++j) {
        float b = bp[(mb + j) * 16 + dl];
#pragma unroll
        for (int rt = 0; rt < 4; ++rt) {
            acc[rt][j][0] = b; acc[rt][j][1] = b; acc[rt][j][2] = b; acc[rt][j][3] = b;
        }
    }

    const int sdl = lane >> 2;    // staging col-within-tile
    const int sj = lane & 3;      // staging k-slot (x8 halves)

    for (int kt = 0; kt < KT; ++kt) {
        const f16* Ap = A0;
        const int pi = kt >> 2;
        if (pi == 1) Ap = A1;
        if (pi == 2) Ap = A2;
        const int kk = (kt & 3) * 32;   // A-part-local k offset

        // stage B: wave-private tiles (w*8..w*8+7 block-local); k-offset GLOBAL kt*32
#pragma unroll
        for (int i = 0; i < 8; ++i) {
            int m = mb + i;                       // global tile
            int ml = (w << 3) + i;                // block-local tile
            async_copy16(Bp + (size_t)(m * 16 + sdl) * K + kt * 32 + (sj << 3),
                         (f16*)Bs + (ml << 9));
        }
        // A-frags direct from global
        half8 a[4];
#pragma unroll
        for (int rt = 0; rt < 4; ++rt)
            a[rt] = *(const half8*)&Ap[(size_t)(row0 + rt * 16 + dl) * 128 + kk + (quad << 3)];
        __syncthreads();  // drains vmcnt(0): staging visible (tiles wave-private; 1 barrier/kt)

#pragma unroll
        for (int hh = 0; hh < 2; ++hh) {
            half8 b[4];
#pragma unroll
            for (int q = 0; q < 4; ++q) {
                int ml = (w << 3) + (hh << 2) + q;
                b[q] = *(const half8*)&Bs[(ml << 9) + (dl << 5) + (quad << 3)];
            }
#pragma unroll
            for (int rt = 0; rt < 4; ++rt)
#pragma unroll
                for (int q = 0; q < 4; ++q)
                    acc[rt][(hh << 2) + q] =
                        __builtin_amdgcn_mfma_f32_16x16x32_f16(a[rt], b[q], acc[rt][(hh << 2) + q], 0, 0, 0);
        }
    }

    // epilogue: lane owns dim d = (4cb + 2w + hh)*16 + dl; i,f,g,o lane-local
#pragma unroll
    for (int hh = 0; hh < 2; ++hh) {
        const int d = (4 * cb + 2 * w + hh) * 16 + dl;
#pragma unroll
        for (int rt = 0; rt < 4; ++rt) {
#pragma unroll
            for (int r = 0; r < 4; ++r) {
                int n = row0 + rt * 16 + (quad << 2) + r;
                if (n < nrows) {
                    float ig = fast_sigmoid(acc[rt][(hh << 2) + 0][r]);
                    float fg = fast_sigmoid(acc[rt][(hh << 2) + 1][r]);
                    float gg = fast_tanh(acc[rt][(hh << 2) + 2][r]);
                    float og = fast_sigmoid(acc[rt][(hh << 2) + 3][r]);
                    float cold = c[(size_t)n * 128 + d];
                    float cn = fg * cold + ig * gg;
                    c[(size_t)n * 128 + d] = cn;
                    h_out[(size_t)n * 128 + d] = (f16)(og * fast_tanh(cn));
                }
            }
        }
    }
}

// ---------------- output projection ----------------
__global__ void out_kernel(const f16* __restrict__ h2, const float* __restrict__ Wout,
                           const float* __restrict__ bout, float* __restrict__ out) {
    int n = blockIdx.x;
    int l = threadIdx.x;  // 0..63
    float v = (float)h2[(size_t)n * 128 + l] * Wout[l] +
              (float)h2[(size_t)n * 128 + 64 + l] * Wout[64 + l];
#pragma unroll
    for (int o = 32; o > 0; o >>= 1) v += __shfl_down(v, o, 64);
    if (l == 0) out[n] = v + bout[0];
}

// ---------------- launch ----------------
extern "C" void kernel_launch(void* const* d_in, const int* in_sizes, int n_in,
                              void* d_out, int out_size, void* d_ws, size_t ws_size,
                              hipStream_t stream) {
    const float* features = (const float*)d_in[0];
    const int*   src      = (const int*)d_in[1];
    const int*   dst      = (const int*)d_in[2];
    const float* W_in     = (const float*)d_in[3];
    const float* b_in     = (const float*)d_in[4];
    const float* Wih0     = (const float*)d_in[5];
    const float* Wih_rest = (const float*)d_in[6];
    const float* Whh      = (const float*)d_in[7];
    const float* bih      = (const float*)d_in[8];
    const float* bhh      = (const float*)d_in[9];
    const float* W_out    = (const float*)d_in[10];
    const float* b_out    = (const float*)d_in[11];
    float* out = (float*)d_out;

    const int N = in_sizes[0] / 6;  // 20000
    const int E = in_sizes[1];      // 640000
    const int NP = N + BM;          // padded rows: A-frag loads never OOB

    char* ws = (char*)d_ws;
    size_t pos = 0;
    auto alloc = [&](size_t bytes) -> void* {
        void* p = ws + pos;
        pos = (pos + bytes + 255) & ~(size_t)255;
        return p;
    };
    const size_t hrow = 128;
    const size_t hbytes = (size_t)NP * hrow * sizeof(f16);
    const size_t cbytes = (size_t)NP * hrow * sizeof(float);
    f16* feath = (f16*)alloc(hbytes);
    f16* aggh  = (f16*)alloc(hbytes);
    f16* hblk  = (f16*)alloc(6 * hbytes);   // ping-pong: A-set then B-set
    f16* hA[3], * hB[3];
    for (int l = 0; l < 3; ++l) {
        hA[l] = hblk + (size_t)l * NP * hrow;
        hB[l] = hblk + (size_t)(l + 3) * NP * hrow;
    }
    float* cblk = (float*)alloc(3 * cbytes);
    float* c0 = cblk + 0 * (size_t)NP * hrow;
    float* c1 = cblk + 1 * (size_t)NP * hrow;
    float* c2 = cblk + 2 * (size_t)NP * hrow;
    f16* Bp0 = (f16*)alloc((size_t)512 * 384 * sizeof(f16));
    f16* Bp1 = (f16*)alloc((size_t)512 * 256 * sizeof(f16));
    f16* Bp2 = (f16*)alloc((size_t)512 * 256 * sizeof(f16));
    float* bp0 = (float*)alloc(512 * sizeof(float));
    float* bp1 = (float*)alloc(512 * sizeof(float));
    float* bp2 = (float*)alloc(512 * sizeof(float));
    int*   cnt   = (int*)alloc((size_t)N * 4);
    int*   offs  = (int*)alloc((size_t)(N + 1) * 4);
    int*   cur   = (int*)alloc((size_t)N * 4);
    int*   esrc  = (int*)alloc((size_t)E * 4);
    float* recip = (float*)alloc((size_t)N * 4);

    hipMemsetAsync(hblk, 0, 6 * hbytes, stream);
    hipMemsetAsync(cblk, 0, 3 * cbytes, stream);
    hipMemsetAsync(cnt, 0, (size_t)N * 4, stream);

    packb_kernel<<<(512 * 384 + 255) / 256, 256, 0, stream>>>(
        Wih0, 256, Whh, 384, bih, bhh, Bp0, bp0);
    packb_kernel<<<(512 * 256 + 255) / 256, 256, 0, stream>>>(
        Wih_rest, 128, Whh + 512 * 128, 256, bih + 512, bhh + 512, Bp1, bp1);
    packb_kernel<<<(512 * 256 + 255) / 256, 256, 0, stream>>>(
        Wih_rest + 512 * 128, 128, Whh + 2 * 512 * 128, 256, bih + 1024, bhh + 1024, Bp2, bp2);

    feat0_kernel<<<(N * 128 + 255) / 256, 256, 0, stream>>>(features, W_in, b_in, feath, N);
    hist_kernel<<<(E + 255) / 256, 256, 0, stream>>>(dst, cnt, E);
    scan_kernel<<<1, 1024, 0, stream>>>(cnt, offs, cur, recip, N);
    scatter_kernel<<<(E + 255) / 256, 256, 0, stream>>>(src, dst, cur, esrc, E);

    const dim3 ggrid((N + BM - 1) / BM, 2, 1);
    const int gagg = (N + 15) / 16;
    const f16* featcur = feath;
    f16 *r0 = hA[0], *r1 = hA[1], *r2 = hA[2];   // read (old state)
    f16 *w0 = hB[0], *w1 = hB[1], *w2 = hB[2];   // write (new state)
    for (int step = 0; step < 11; ++step) {
        agg_kernel<<<gagg, 256, 0, stream>>>(featcur, offs, esrc, recip, aggh, N);
        gemm_lstm<12><<<ggrid, 128, 0, stream>>>(aggh, featcur, r0, Bp0, bp0, c0, w0, N);
        gemm_lstm<8><<<ggrid, 128, 0, stream>>>(w0, r1, nullptr, Bp1, bp1, c1, w1, N);
        gemm_lstm<8><<<ggrid, 128, 0, stream>>>(w1, r2, nullptr, Bp2, bp2, c2, w2, N);
        featcur = w2;
        f16* t;
        t = r0; r0 = w0; w0 = t;
        t = r1; r1 = w1; w1 = t;
        t = r2; r2 = w2; w2 = t;
    }
    out_kernel<<<N, 64, 0, stream>>>((const f16*)featcur, W_out, b_out, out);
}